// Round 3
// baseline (403.183 us; speedup 1.0000x reference)
//
#include <hip/hip_runtime.h>
#include <hip/hip_cooperative_groups.h>
#include <math.h>

namespace cg = cooperative_groups;

// Problem constants (from reference)
#define NN 1024      // N
#define DD 64        // D
#define TT 2048      // T
#define UDEC 0.97f
#define EPS 1e-6f
// rho/a* chunking
#define CC 64        // chunk length along t
#define NCH 32       // TT/CC
// P3 slicing (width 128)
#define SL3 128
// P5 slicing (width 64 -> LDS tile pair fits well under 64 KiB)
#define NS5 16
#define SL5 64
// X prefix-scan chunking
#define C2 32
#define NC2 64       // TT/C2

// LDS reused phase-by-phase via union; max member = SP3 (49,668 B) < 64 KiB.
struct SP1 { float Vs[C2][DD]; };
struct SP3 { float Xs[CC][SL3 + 1]; float Vw[CC][DD]; float pw[CC + 1]; };
struct SP5 { float Xs[CC][SL5 + 1]; float Rs[CC][SL5 + 1]; };
struct SP6 { float Gs[8][CC + 1]; float Ps[8][DD]; float Ve[CC][DD]; float pw[CC + 1]; };
struct SP7 { float L[8][DD]; float Ys[8][NN]; float pre[8][DD + 1]; float mrow[8]; float srow[8]; };
union SMem { SP1 p1; SP3 p3; SP5 p5; SP6 p6; SP7 p7; };

struct KP {
    const float *E, *Dx, *Dy, *temb, *x0, *rho0;
    const int* toks;
    float *ys, *vs;
    float *Xp, *S, *Bb, *M, *Rho, *Gp, *Pp, *LNA;
};

// ---------------- P1: X intra-chunk inclusive prefix + chunk totals ----------------
__device__ __forceinline__ void phase1(const KP& p, SMem& sm, int bid, int tid) {
    const int cs = bid >> 2;                      // 0..63
    const int n  = (bid & 3) * 256 + tid;         // 0..1023
    for (int i = tid; i < C2 * DD; i += 256) {
        int s = i >> 6, d = i & 63;
        sm.p1.Vs[s][d] = p.temb[p.toks[cs * C2 + s] * DD + d];
    }
    __syncthreads();
    float dxr[DD];
    const float4* dx4 = reinterpret_cast<const float4*>(p.Dx + n * DD);
#pragma unroll
    for (int j = 0; j < 16; ++j) {
        float4 v = dx4[j];
        dxr[4*j] = v.x; dxr[4*j+1] = v.y; dxr[4*j+2] = v.z; dxr[4*j+3] = v.w;
    }
    float run = 0.f;
    for (int s = 0; s < C2; ++s) {
        const float4* vr = reinterpret_cast<const float4*>(&sm.p1.Vs[s][0]); // broadcast
        float a0 = 0.f, a1 = 0.f, a2 = 0.f, a3 = 0.f;
#pragma unroll
        for (int j = 0; j < 16; ++j) {
            float4 v = vr[j];
            a0 += v.x * dxr[4*j];   a1 += v.y * dxr[4*j+1];
            a2 += v.z * dxr[4*j+2]; a3 += v.w * dxr[4*j+3];
        }
        run += fmaxf((a0 + a1) + (a2 + a3), 0.f);
        p.Xp[(cs * C2 + s) * NN + n] = run;
    }
    p.S[cs * NN + n] = run;
}

// ---------------- P2: serial scan of 64 chunk totals (4 blocks) ----------------
__device__ __forceinline__ void phase2(const KP& p, int bid, int tid) {
    const int n = bid * 256 + tid;
    float acc = p.x0[n];
    for (int cs = 0; cs < NC2; ++cs) {
        p.Bb[cs * NN + n] = acc;
        acc += p.S[cs * NN + n];
    }
}
// True X[t][n] = Xp[t][n] + Bb[t/32][n].

// ---------------- P3: per-chunk rank collapse M_c[d][n] ----------------
__device__ __forceinline__ void phase3(const KP& p, SMem& sm, int bid, int tid) {
    const int c = bid >> 3, q = bid & 7;
    if (tid <= CC) sm.p3.pw[tid] = powf(UDEC, (float)tid);
    __syncthreads();
    for (int i = tid; i < CC * SL3; i += 256) {
        int s = i / SL3, n = i % SL3;
        int t = c * CC + s, gn = q * SL3 + n;
        sm.p3.Xs[s][n] = p.Xp[t * NN + gn] + p.Bb[(t >> 5) * NN + gn];
    }
    for (int i = tid; i < CC * DD; i += 256) {
        int s = i >> 6, d = i & 63;
        sm.p3.Vw[s][d] = p.temb[p.toks[c * CC + s] * DD + d] * sm.p3.pw[CC - s];
    }
    __syncthreads();
    const int n_l = tid & 127;
    const int dh  = tid >> 7;
    float acc[32];
#pragma unroll
    for (int k = 0; k < 32; ++k) acc[k] = 0.f;
    for (int s = 0; s < CC; ++s) {
        float xv = sm.p3.Xs[s][n_l];
        const float4* vr = reinterpret_cast<const float4*>(&sm.p3.Vw[s][dh * 32]);
#pragma unroll
        for (int k8 = 0; k8 < 8; ++k8) {
            float4 v = vr[k8];
            acc[4*k8]   += v.x * xv;  acc[4*k8+1] += v.y * xv;
            acc[4*k8+2] += v.z * xv;  acc[4*k8+3] += v.w * xv;
        }
    }
    for (int k = 0; k < 32; ++k)
        p.M[(c * DD + dh * 32 + k) * NN + q * SL3 + n_l] = acc[k];
}

// ---------------- P4: elementwise chunk scan Rho[c] ----------------
__device__ __forceinline__ void phase4(const KP& p, int bid, int tid) {
    const int el = bid * 256 + tid;               // exactly DD*NN threads
    const float uc = powf(UDEC, (float)CC);
    float acc = p.rho0[el];
#pragma unroll
    for (int c = 0; c < NCH; ++c) {
        p.Rho[c * (DD * NN) + el] = acc;
        acc = fmaf(acc, uc, p.M[c * (DD * NN) + el]);
    }
}

// ---------------- P5: partial Gram Gp + inter Pp, one work item = (chunk, slice) ----------------
__device__ __forceinline__ void phase5(const KP& p, SMem& sm, int work, int tid) {
    const int c = work >> 4, q = work & 15;       // 512 work items
    for (int i = tid; i < CC * SL5; i += 256) {
        int s = i >> 6, n = i & 63;
        int t = c * CC + s, gn = q * SL5 + n;
        sm.p5.Xs[s][n] = p.Xp[t * NN + gn] + p.Bb[(t >> 5) * NN + gn];
        sm.p5.Rs[s][n] = p.Rho[(c * DD + s) * NN + gn];   // DD==CC rows
    }
    __syncthreads();
    const int ti = tid >> 4;   // t = ti*4+a
    const int sj = tid & 15;   // s/d = sj*4+b
    float accG[16], accP[16];
#pragma unroll
    for (int k = 0; k < 16; ++k) { accG[k] = 0.f; accP[k] = 0.f; }
    for (int n = 0; n < SL5; ++n) {
        float xt[4], xs[4], rv[4];
#pragma unroll
        for (int a = 0; a < 4; ++a) xt[a] = sm.p5.Xs[ti * 4 + a][n];
#pragma unroll
        for (int b = 0; b < 4; ++b) { xs[b] = sm.p5.Xs[sj * 4 + b][n]; rv[b] = sm.p5.Rs[sj * 4 + b][n]; }
#pragma unroll
        for (int a = 0; a < 4; ++a)
#pragma unroll
            for (int b = 0; b < 4; ++b) {
                accG[a * 4 + b] += xt[a] * xs[b];
                accP[a * 4 + b] += xt[a] * rv[b];
            }
    }
    float* gbase = p.Gp + ((size_t)(c * NS5 + q) * CC) * CC;
    float* pbase = p.Pp + ((size_t)(c * NS5 + q) * CC) * DD;
#pragma unroll
    for (int a = 0; a < 4; ++a) {
        *reinterpret_cast<float4*>(gbase + (ti * 4 + a) * CC + sj * 4) =
            make_float4(accG[a*4], accG[a*4+1], accG[a*4+2], accG[a*4+3]);
        *reinterpret_cast<float4*>(pbase + (ti * 4 + a) * DD + sj * 4) =
            make_float4(accP[a*4], accP[a*4+1], accP[a*4+2], accP[a*4+3]);
    }
}

// ---------------- P6: slice-reduce + decay-weighted a* + LN(ddof=1) ----------------
__device__ __forceinline__ void phase6(const KP& p, SMem& sm, int bid, int tid) {
    const int c = bid >> 3, rg = bid & 7;         // rows rg*8..rg*8+7 of chunk c
    if (tid <= CC) sm.p6.pw[tid] = powf(UDEC, (float)tid);
    for (int i = tid; i < 8 * CC; i += 256) {
        int r = i >> 6, s2 = i & 63;
        int t = rg * 8 + r;
        float ag = 0.f, ap = 0.f;
#pragma unroll
        for (int qq = 0; qq < NS5; ++qq) {
            ag += p.Gp[((size_t)(c * NS5 + qq) * CC + t) * CC + s2];
            ap += p.Pp[((size_t)(c * NS5 + qq) * CC + t) * DD + s2];
        }
        sm.p6.Gs[r][s2] = ag;
        sm.p6.Ps[r][s2] = ap;
    }
    for (int i = tid; i < CC * DD; i += 256) {
        int s2 = i >> 6, d = i & 63;
        sm.p6.Ve[s2][d] = p.temb[p.toks[c * CC + s2] * DD + d];
    }
    __syncthreads();
    const int r   = tid >> 5;                     // 0..7
    const int dh  = tid & 31;                     // owns d = 2*dh, 2*dh+1
    const int t_l = rg * 8 + r;
    float a0 = sm.p6.pw[t_l] * sm.p6.Ps[r][2 * dh];
    float a1 = sm.p6.pw[t_l] * sm.p6.Ps[r][2 * dh + 1];
    for (int s2 = 0; s2 < t_l; ++s2) {
        float w = sm.p6.pw[t_l - s2] * sm.p6.Gs[r][s2];   // broadcast read
        a0 += w * sm.p6.Ve[s2][2 * dh];
        a1 += w * sm.p6.Ve[s2][2 * dh + 1];
    }
    // LN across the 32 lanes of this row (xor masks <32 stay within the 32-lane group)
    float ssum = a0 + a1;
#pragma unroll
    for (int m = 16; m >= 1; m >>= 1) ssum += __shfl_xor(ssum, m, 64);
    float mean = ssum * (1.f / DD);
    float z0 = a0 - mean, z1 = a1 - mean;
    float vsum = z0 * z0 + z1 * z1;
#pragma unroll
    for (int m = 16; m >= 1; m >>= 1) vsum += __shfl_xor(vsum, m, 64);
    float inv = 1.f / (sqrtf(vsum * (1.f / (DD - 1))) + EPS);
    int t = c * CC + t_l;
    *reinterpret_cast<float2*>(&p.LNA[t * DD + 2 * dh]) = make_float2(z0 * inv, z1 * inv);
}

// ---------------- P7: y = relu(Dy@LNA)*relu(x); v = LN(E@y) ----------------
__device__ __forceinline__ void phase7(const KP& p, SMem& sm, int bid, int tid) {
    const int t0 = bid * 8;
    for (int i = tid; i < 8 * DD; i += 256)
        sm.p7.L[i >> 6][i & 63] = p.LNA[t0 * DD + i];
    __syncthreads();
    for (int nq = 0; nq < 4; ++nq) {
        const int n = nq * 256 + tid;
        float dyr[DD];
        const float4* dy4 = reinterpret_cast<const float4*>(p.Dy + n * DD);
#pragma unroll
        for (int j = 0; j < 16; ++j) {
            float4 v = dy4[j];
            dyr[4*j] = v.x; dyr[4*j+1] = v.y; dyr[4*j+2] = v.z; dyr[4*j+3] = v.w;
        }
#pragma unroll
        for (int r = 0; r < 8; ++r) {
            const float4* lr = reinterpret_cast<const float4*>(&sm.p7.L[r][0]);
            float a0 = 0.f, a1 = 0.f, a2 = 0.f, a3 = 0.f;
#pragma unroll
            for (int j = 0; j < 16; ++j) {
                float4 v = lr[j];
                a0 += v.x * dyr[4*j];   a1 += v.y * dyr[4*j+1];
                a2 += v.z * dyr[4*j+2]; a3 += v.w * dyr[4*j+3];
            }
            float yc = (a0 + a1) + (a2 + a3);
            int t = t0 + r;
            float xv = p.Xp[t * NN + n] + p.Bb[(t >> 5) * NN + n];
            float yv = fmaxf(yc, 0.f) * fmaxf(xv, 0.f);
            p.ys[t * NN + n] = yv;
            sm.p7.Ys[r][n] = yv;
        }
    }
    __syncthreads();
    const int d  = tid & 63;
    const int r0 = (tid >> 6) * 2;
    const float4* e4 = reinterpret_cast<const float4*>(p.E + d * NN);
    float a00=0,a01=0,a02=0,a03=0, a10=0,a11=0,a12=0,a13=0;
    for (int j = 0; j < NN / 4; ++j) {
        float4 ev  = e4[j];
        float4 y0v = *reinterpret_cast<const float4*>(&sm.p7.Ys[r0][4 * j]);     // broadcast
        float4 y1v = *reinterpret_cast<const float4*>(&sm.p7.Ys[r0 + 1][4 * j]); // broadcast
        a00 += ev.x * y0v.x; a01 += ev.y * y0v.y; a02 += ev.z * y0v.z; a03 += ev.w * y0v.w;
        a10 += ev.x * y1v.x; a11 += ev.y * y1v.y; a12 += ev.z * y1v.z; a13 += ev.w * y1v.w;
    }
    sm.p7.pre[r0][d]     = (a00 + a01) + (a02 + a03);
    sm.p7.pre[r0 + 1][d] = (a10 + a11) + (a12 + a13);
    __syncthreads();
    if (tid < 8) {
        float m = 0.f;
#pragma unroll
        for (int dd2 = 0; dd2 < DD; ++dd2) m += sm.p7.pre[tid][dd2];
        m *= (1.f / DD);
        float v = 0.f;
#pragma unroll
        for (int dd2 = 0; dd2 < DD; ++dd2) { float z = sm.p7.pre[tid][dd2] - m; v += z * z; }
        sm.p7.mrow[tid] = m;
        sm.p7.srow[tid] = 1.f / (sqrtf(v / (DD - 1)) + EPS);
    }
    __syncthreads();
    for (int i = tid; i < 8 * DD; i += 256) {
        int r = i >> 6, dd2 = i & 63;
        p.vs[(t0 + r) * DD + dd2] = (sm.p7.pre[r][dd2] - sm.p7.mrow[r]) * sm.p7.srow[r];
    }
}

// ---------------- fused cooperative kernel ----------------
__global__ __launch_bounds__(256) void fused(KP p) {
    cg::grid_group grid = cg::this_grid();
    __shared__ SMem sm;
    const int tid = threadIdx.x;
    const int bid = blockIdx.x;
    phase1(p, sm, bid, tid);
    grid.sync();
    if (bid < 4) phase2(p, bid, tid);
    grid.sync();
    phase3(p, sm, bid, tid);
    grid.sync();
    phase4(p, bid, tid);
    grid.sync();
    phase5(p, sm, 2 * bid, tid);
    __syncthreads();
    phase5(p, sm, 2 * bid + 1, tid);
    grid.sync();
    phase6(p, sm, bid, tid);
    grid.sync();
    phase7(p, sm, bid, tid);
}

// ---------------- non-cooperative fallback wrappers ----------------
__global__ __launch_bounds__(256) void kP1(KP p) { __shared__ SMem sm; phase1(p, sm, blockIdx.x, threadIdx.x); }
__global__ __launch_bounds__(256) void kP2(KP p) { phase2(p, blockIdx.x, threadIdx.x); }
__global__ __launch_bounds__(256) void kP3(KP p) { __shared__ SMem sm; phase3(p, sm, blockIdx.x, threadIdx.x); }
__global__ __launch_bounds__(256) void kP4(KP p) { phase4(p, blockIdx.x, threadIdx.x); }
__global__ __launch_bounds__(256) void kP5(KP p) { __shared__ SMem sm; phase5(p, sm, blockIdx.x, threadIdx.x); }
__global__ __launch_bounds__(256) void kP6(KP p) { __shared__ SMem sm; phase6(p, sm, blockIdx.x, threadIdx.x); }
__global__ __launch_bounds__(256) void kP7(KP p) { __shared__ SMem sm; phase7(p, sm, blockIdx.x, threadIdx.x); }

// ---------------------------------------------------------------------------
extern "C" void kernel_launch(void* const* d_in, const int* in_sizes, int n_in,
                              void* d_out, int out_size, void* d_ws, size_t ws_size,
                              hipStream_t stream) {
    (void)in_sizes; (void)n_in; (void)out_size; (void)ws_size;
    KP p;
    p.E    = (const float*)d_in[0];   // [D,N]
    p.Dx   = (const float*)d_in[1];   // [N,D]
    p.Dy   = (const float*)d_in[2];   // [N,D]
    p.temb = (const float*)d_in[3];   // [V,D]
    p.x0   = (const float*)d_in[4];   // [N]
    p.rho0 = (const float*)d_in[5];   // [D,N]
    p.toks = (const int*)d_in[6];     // [T]

    p.ys = (float*)d_out;                    // [T,N]
    p.vs = p.ys + (size_t)TT * NN;           // [T,D]

    float* w = (float*)d_ws;                 // ~41 MiB used
    p.Xp  = w;                                       // TT*NN
    p.S   = p.Xp  + (size_t)TT * NN;                 // NC2*NN
    p.Bb  = p.S   + (size_t)NC2 * NN;                // NC2*NN
    p.M   = p.Bb  + (size_t)NC2 * NN;                // NCH*DD*NN
    p.Rho = p.M   + (size_t)NCH * DD * NN;           // NCH*DD*NN
    p.Gp  = p.Rho + (size_t)NCH * DD * NN;           // NCH*NS5*CC*CC
    p.Pp  = p.Gp  + (size_t)NCH * NS5 * CC * CC;     // NCH*NS5*CC*DD
    p.LNA = p.Pp  + (size_t)NCH * NS5 * CC * DD;     // TT*DD

    void* args[] = { &p };
    hipError_t err = hipLaunchCooperativeKernel((const void*)fused, dim3(256), dim3(256),
                                                args, 0, stream);
    if (err != hipSuccess) {
        (void)hipGetLastError();             // clear sticky error, run phase-split path
        kP1<<<dim3(256), 256, 0, stream>>>(p);
        kP2<<<dim3(4),   256, 0, stream>>>(p);
        kP3<<<dim3(256), 256, 0, stream>>>(p);
        kP4<<<dim3(256), 256, 0, stream>>>(p);
        kP5<<<dim3(512), 256, 0, stream>>>(p);
        kP6<<<dim3(256), 256, 0, stream>>>(p);
        kP7<<<dim3(256), 256, 0, stream>>>(p);
    }
}

// Round 4
// 227.424 us; speedup vs baseline: 1.7728x; 1.7728x over previous
//
#include <hip/hip_runtime.h>
#include <math.h>

// Problem constants (from reference)
#define NN 1024      // N
#define DD 64        // D
#define TT 2048      // T
#define UDEC 0.97f
#define EPS 1e-6f
// rho/a* chunking
#define CC 64        // chunk length along t
#define NCH 32       // TT/CC
// P3/P5 slicing: 16 slices of width 64 -> grid 512, 2 blocks/CU
#define NSL 16
#define SLW 64
// X prefix-scan chunking: 128 chunks of 16 -> grid 512, 2 blocks/CU
#define C2 16
#define NC2 128      // TT/C2
#define C2SH 4       // log2(C2)

struct KP {
    const float *E, *Dx, *Dy, *temb, *x0, *rho0;
    const int* toks;
    float *ys, *vs;
    float *Xp, *S, *Bb, *M, *Rho, *Gp, *Pp, *LNA;
};

// True X[t][n] = Xp[t][n] + Bb[t>>C2SH][n].

// ---------------- K1: X intra-chunk inclusive prefix + chunk totals ----------------
// grid 512 (128 chunks x 4 n-quarters), block 256. LDS 4 KB.
__global__ __launch_bounds__(256) void k1_xscan(KP p) {
    __shared__ float Vs[C2][DD];
    const int tid = threadIdx.x;
    const int cs = blockIdx.x >> 2;               // 0..127
    const int n  = (blockIdx.x & 3) * 256 + tid;  // 0..1023
    for (int i = tid; i < C2 * DD; i += 256) {
        int s = i >> 6, d = i & 63;
        Vs[s][d] = p.temb[p.toks[cs * C2 + s] * DD + d];
    }
    __syncthreads();
    float dxr[DD];
    const float4* dx4 = reinterpret_cast<const float4*>(p.Dx + n * DD);
#pragma unroll
    for (int j = 0; j < 16; ++j) {
        float4 v = dx4[j];
        dxr[4*j] = v.x; dxr[4*j+1] = v.y; dxr[4*j+2] = v.z; dxr[4*j+3] = v.w;
    }
    float run = 0.f;
#pragma unroll
    for (int s = 0; s < C2; ++s) {
        const float4* vr = reinterpret_cast<const float4*>(&Vs[s][0]);  // broadcast
        float a0 = 0.f, a1 = 0.f, a2 = 0.f, a3 = 0.f;
#pragma unroll
        for (int j = 0; j < 16; ++j) {
            float4 v = vr[j];
            a0 += v.x * dxr[4*j];   a1 += v.y * dxr[4*j+1];
            a2 += v.z * dxr[4*j+2]; a3 += v.w * dxr[4*j+3];
        }
        run += fmaxf((a0 + a1) + (a2 + a3), 0.f);
        p.Xp[(cs * C2 + s) * NN + n] = run;
    }
    p.S[cs * NN + n] = run;
}

// ---------------- K2: serial scan of 128 chunk totals ----------------
// grid 8, block 128 (1024 threads total, one per n).
__global__ __launch_bounds__(128) void k2_base(KP p) {
    const int n = blockIdx.x * 128 + threadIdx.x;
    float acc = p.x0[n];
#pragma unroll 16
    for (int cs = 0; cs < NC2; ++cs) {
        p.Bb[cs * NN + n] = acc;
        acc += p.S[cs * NN + n];
    }
}

// ---------------- K3: per-chunk rank collapse M_c[d][n] ----------------
// grid 512 (32 chunks x 16 slices of width 64), block 256. LDS ~33 KB.
__global__ __launch_bounds__(256) void k3_M(KP p) {
    __shared__ float Xs[CC][SLW + 1];
    __shared__ float Vw[CC][DD];
    __shared__ float pw[CC + 1];
    const int tid = threadIdx.x;
    const int c = blockIdx.x >> 4, q = blockIdx.x & 15;
    if (tid <= CC) pw[tid] = powf(UDEC, (float)tid);
    __syncthreads();
    for (int i = tid; i < CC * SLW; i += 256) {
        int s = i >> 6, n = i & 63;
        int t = c * CC + s, gn = q * SLW + n;
        Xs[s][n] = p.Xp[t * NN + gn] + p.Bb[(t >> C2SH) * NN + gn];
    }
    for (int i = tid; i < CC * DD; i += 256) {
        int s = i >> 6, d = i & 63;
        Vw[s][d] = p.temb[p.toks[c * CC + s] * DD + d] * pw[CC - s];
    }
    __syncthreads();
    const int n_l = tid & 63;
    const int dh  = tid >> 6;                     // 0..3 -> d = dh*16 + k
    float acc[16];
#pragma unroll
    for (int k = 0; k < 16; ++k) acc[k] = 0.f;
    for (int s = 0; s < CC; ++s) {
        float xv = Xs[s][n_l];
        const float4* vr = reinterpret_cast<const float4*>(&Vw[s][dh * 16]);
#pragma unroll
        for (int k4 = 0; k4 < 4; ++k4) {
            float4 v = vr[k4];
            acc[4*k4]   += v.x * xv;  acc[4*k4+1] += v.y * xv;
            acc[4*k4+2] += v.z * xv;  acc[4*k4+3] += v.w * xv;
        }
    }
#pragma unroll
    for (int k = 0; k < 16; ++k)
        p.M[(c * DD + dh * 16 + k) * NN + q * SLW + n_l] = acc[k];
}

// ---------------- K4: elementwise chunk scan Rho[c] ----------------
// grid 256, block 256 (one thread per (d,n)).
__global__ __launch_bounds__(256) void k4_rho(KP p) {
    const int el = blockIdx.x * 256 + threadIdx.x;
    const float uc = powf(UDEC, (float)CC);
    float acc = p.rho0[el];
#pragma unroll
    for (int c = 0; c < NCH; ++c) {
        p.Rho[c * (DD * NN) + el] = acc;
        acc = fmaf(acc, uc, p.M[c * (DD * NN) + el]);
    }
}

// ---------------- K5: partial Gram Gp + inter Pp ----------------
// grid 512 (32 chunks x 16 slices of width 64), block 256. LDS ~33 KB.
__global__ __launch_bounds__(256) void k5_gram(KP p) {
    __shared__ float Xs[CC][SLW + 1];
    __shared__ float Rs[CC][SLW + 1];
    const int tid = threadIdx.x;
    const int c = blockIdx.x >> 4, q = blockIdx.x & 15;
    for (int i = tid; i < CC * SLW; i += 256) {
        int s = i >> 6, n = i & 63;
        int t = c * CC + s, gn = q * SLW + n;
        Xs[s][n] = p.Xp[t * NN + gn] + p.Bb[(t >> C2SH) * NN + gn];
        Rs[s][n] = p.Rho[(c * DD + s) * NN + gn];   // DD==CC rows
    }
    __syncthreads();
    const int ti = tid >> 4;   // t = ti*4+a
    const int sj = tid & 15;   // s/d = sj*4+b
    float accG[16], accP[16];
#pragma unroll
    for (int k = 0; k < 16; ++k) { accG[k] = 0.f; accP[k] = 0.f; }
    for (int n = 0; n < SLW; ++n) {
        float xt[4], xs[4], rv[4];
#pragma unroll
        for (int a = 0; a < 4; ++a) xt[a] = Xs[ti * 4 + a][n];
#pragma unroll
        for (int b = 0; b < 4; ++b) { xs[b] = Xs[sj * 4 + b][n]; rv[b] = Rs[sj * 4 + b][n]; }
#pragma unroll
        for (int a = 0; a < 4; ++a)
#pragma unroll
            for (int b = 0; b < 4; ++b) {
                accG[a * 4 + b] += xt[a] * xs[b];
                accP[a * 4 + b] += xt[a] * rv[b];
            }
    }
    float* gbase = p.Gp + ((size_t)(c * NSL + q) * CC) * CC;
    float* pbase = p.Pp + ((size_t)(c * NSL + q) * CC) * DD;
#pragma unroll
    for (int a = 0; a < 4; ++a) {
        *reinterpret_cast<float4*>(gbase + (ti * 4 + a) * CC + sj * 4) =
            make_float4(accG[a*4], accG[a*4+1], accG[a*4+2], accG[a*4+3]);
        *reinterpret_cast<float4*>(pbase + (ti * 4 + a) * DD + sj * 4) =
            make_float4(accP[a*4], accP[a*4+1], accP[a*4+2], accP[a*4+3]);
    }
}

// ---------------- K6: slice-reduce + decay-weighted a* + LN(ddof=1) ----------------
// grid 256 (32 chunks x 8 row-groups), block 256.
__global__ __launch_bounds__(256) void k6_astar(KP p) {
    __shared__ float Gs[8][CC + 1];
    __shared__ float Ps[8][DD];
    __shared__ float Ve[CC][DD];
    __shared__ float pw[CC + 1];
    const int tid = threadIdx.x;
    const int c = blockIdx.x >> 3, rg = blockIdx.x & 7;   // rows rg*8..rg*8+7
    if (tid <= CC) pw[tid] = powf(UDEC, (float)tid);
    for (int i = tid; i < 8 * CC; i += 256) {
        int r = i >> 6, s2 = i & 63;
        int t = rg * 8 + r;
        float ag = 0.f, ap = 0.f;
#pragma unroll
        for (int qq = 0; qq < NSL; ++qq) {
            ag += p.Gp[((size_t)(c * NSL + qq) * CC + t) * CC + s2];
            ap += p.Pp[((size_t)(c * NSL + qq) * CC + t) * DD + s2];
        }
        Gs[r][s2] = ag;
        Ps[r][s2] = ap;
    }
    for (int i = tid; i < CC * DD; i += 256) {
        int s2 = i >> 6, d = i & 63;
        Ve[s2][d] = p.temb[p.toks[c * CC + s2] * DD + d];
    }
    __syncthreads();
    const int r   = tid >> 5;                     // 0..7
    const int dh  = tid & 31;                     // owns d = 2*dh, 2*dh+1
    const int t_l = rg * 8 + r;
    float a0 = pw[t_l] * Ps[r][2 * dh];
    float a1 = pw[t_l] * Ps[r][2 * dh + 1];
    for (int s2 = 0; s2 < t_l; ++s2) {
        float w = pw[t_l - s2] * Gs[r][s2];       // broadcast read
        a0 += w * Ve[s2][2 * dh];
        a1 += w * Ve[s2][2 * dh + 1];
    }
    // LN across the 32 lanes of this row (xor masks <32 stay within the 32-lane group)
    float ssum = a0 + a1;
#pragma unroll
    for (int m = 16; m >= 1; m >>= 1) ssum += __shfl_xor(ssum, m, 64);
    float mean = ssum * (1.f / DD);
    float z0 = a0 - mean, z1 = a1 - mean;
    float vsum = z0 * z0 + z1 * z1;
#pragma unroll
    for (int m = 16; m >= 1; m >>= 1) vsum += __shfl_xor(vsum, m, 64);
    float inv = 1.f / (sqrtf(vsum * (1.f / (DD - 1))) + EPS);
    int t = c * CC + t_l;
    *reinterpret_cast<float2*>(&p.LNA[t * DD + 2 * dh]) = make_float2(z0 * inv, z1 * inv);
}

// ---------------- K7: y = relu(Dy@LNA)*relu(x); v = LN(E@y) ----------------
// grid 256 (8 t-rows per block), block 256. LDS ~35 KB.
__global__ __launch_bounds__(256) void k7_yv(KP p) {
    __shared__ float L[8][DD];
    __shared__ float Ys[8][NN];
    __shared__ float pre[8][DD + 1];
    __shared__ float mrow[8], srow[8];
    const int tid = threadIdx.x;
    const int t0 = blockIdx.x * 8;
    for (int i = tid; i < 8 * DD; i += 256)
        L[i >> 6][i & 63] = p.LNA[t0 * DD + i];
    __syncthreads();
    for (int nq = 0; nq < 4; ++nq) {
        const int n = nq * 256 + tid;
        float dyr[DD];
        const float4* dy4 = reinterpret_cast<const float4*>(p.Dy + n * DD);
#pragma unroll
        for (int j = 0; j < 16; ++j) {
            float4 v = dy4[j];
            dyr[4*j] = v.x; dyr[4*j+1] = v.y; dyr[4*j+2] = v.z; dyr[4*j+3] = v.w;
        }
#pragma unroll
        for (int r = 0; r < 8; ++r) {
            const float4* lr = reinterpret_cast<const float4*>(&L[r][0]);
            float a0 = 0.f, a1 = 0.f, a2 = 0.f, a3 = 0.f;
#pragma unroll
            for (int j = 0; j < 16; ++j) {
                float4 v = lr[j];
                a0 += v.x * dyr[4*j];   a1 += v.y * dyr[4*j+1];
                a2 += v.z * dyr[4*j+2]; a3 += v.w * dyr[4*j+3];
            }
            float yc = (a0 + a1) + (a2 + a3);
            int t = t0 + r;
            float xv = p.Xp[t * NN + n] + p.Bb[(t >> C2SH) * NN + n];
            float yv = fmaxf(yc, 0.f) * fmaxf(xv, 0.f);
            p.ys[t * NN + n] = yv;
            Ys[r][n] = yv;
        }
    }
    __syncthreads();
    const int d  = tid & 63;
    const int r0 = (tid >> 6) * 2;
    const float4* e4 = reinterpret_cast<const float4*>(p.E + d * NN);
    float a00=0,a01=0,a02=0,a03=0, a10=0,a11=0,a12=0,a13=0;
    for (int j = 0; j < NN / 4; ++j) {
        float4 ev  = e4[j];
        float4 y0v = *reinterpret_cast<const float4*>(&Ys[r0][4 * j]);     // broadcast
        float4 y1v = *reinterpret_cast<const float4*>(&Ys[r0 + 1][4 * j]); // broadcast
        a00 += ev.x * y0v.x; a01 += ev.y * y0v.y; a02 += ev.z * y0v.z; a03 += ev.w * y0v.w;
        a10 += ev.x * y1v.x; a11 += ev.y * y1v.y; a12 += ev.z * y1v.z; a13 += ev.w * y1v.w;
    }
    pre[r0][d]     = (a00 + a01) + (a02 + a03);
    pre[r0 + 1][d] = (a10 + a11) + (a12 + a13);
    __syncthreads();
    if (tid < 8) {
        float m = 0.f;
#pragma unroll
        for (int dd2 = 0; dd2 < DD; ++dd2) m += pre[tid][dd2];
        m *= (1.f / DD);
        float v = 0.f;
#pragma unroll
        for (int dd2 = 0; dd2 < DD; ++dd2) { float z = pre[tid][dd2] - m; v += z * z; }
        mrow[tid] = m;
        srow[tid] = 1.f / (sqrtf(v / (DD - 1)) + EPS);
    }
    __syncthreads();
    for (int i = tid; i < 8 * DD; i += 256) {
        int r = i >> 6, dd2 = i & 63;
        p.vs[(t0 + r) * DD + dd2] = (pre[r][dd2] - mrow[r]) * srow[r];
    }
}

// ---------------------------------------------------------------------------
extern "C" void kernel_launch(void* const* d_in, const int* in_sizes, int n_in,
                              void* d_out, int out_size, void* d_ws, size_t ws_size,
                              hipStream_t stream) {
    (void)in_sizes; (void)n_in; (void)out_size; (void)ws_size;
    KP p;
    p.E    = (const float*)d_in[0];   // [D,N]
    p.Dx   = (const float*)d_in[1];   // [N,D]
    p.Dy   = (const float*)d_in[2];   // [N,D]
    p.temb = (const float*)d_in[3];   // [V,D]
    p.x0   = (const float*)d_in[4];   // [N]
    p.rho0 = (const float*)d_in[5];   // [D,N]
    p.toks = (const int*)d_in[6];     // [T]

    p.ys = (float*)d_out;                    // [T,N]
    p.vs = p.ys + (size_t)TT * NN;           // [T,D]

    float* w = (float*)d_ws;                 // ~42 MiB used
    p.Xp  = w;                                       // TT*NN
    p.S   = p.Xp  + (size_t)TT * NN;                 // NC2*NN
    p.Bb  = p.S   + (size_t)NC2 * NN;                // NC2*NN
    p.M   = p.Bb  + (size_t)NC2 * NN;                // NCH*DD*NN
    p.Rho = p.M   + (size_t)NCH * DD * NN;           // NCH*DD*NN
    p.Gp  = p.Rho + (size_t)NCH * DD * NN;           // NCH*NSL*CC*CC
    p.Pp  = p.Gp  + (size_t)NCH * NSL * CC * CC;     // NCH*NSL*CC*DD
    p.LNA = p.Pp  + (size_t)NCH * NSL * CC * DD;     // TT*DD

    k1_xscan<<<dim3(512), 256, 0, stream>>>(p);
    k2_base <<<dim3(8),   128, 0, stream>>>(p);
    k3_M    <<<dim3(512), 256, 0, stream>>>(p);
    k4_rho  <<<dim3(256), 256, 0, stream>>>(p);
    k5_gram <<<dim3(512), 256, 0, stream>>>(p);
    k6_astar<<<dim3(256), 256, 0, stream>>>(p);
    k7_yv   <<<dim3(256), 256, 0, stream>>>(p);
}